// Round 9
// baseline (138.757 us; speedup 1.0000x reference)
//
#include <hip/hip_runtime.h>
#include <hip/hip_bf16.h>

// Problem constants
#define BATCH 4
#define S_TOT 4096
#define ROWS (BATCH * S_TOT)   // 16384
#define DM 2048
#define DSP 128
#define NSEG 512               // neurons per segment; 3 segments

typedef short short8 __attribute__((ext_vector_type(8)));
typedef float f32x16 __attribute__((ext_vector_type(16)));

// float -> bf16(RNE) bits; also returns the fp32 value of the bf16 for residual
static __device__ inline short f2bf(float v, float& back) {
  unsigned u = __float_as_uint(v);
  unsigned r = u + 0x7FFFu + ((u >> 16) & 1u);
  unsigned short hs = (unsigned short)(r >> 16);
  back = __uint_as_float(((unsigned)hs) << 16);
  return (short)hs;
}

// packed f32x2 -> bf16x2 (hw instr). Lo term is exact residual of hi's value,
// so the split is correct regardless of cvt rounding mode.
static __device__ inline unsigned cvtpk2(float a, float b) {
  unsigned r;
  asm("v_cvt_pk_bf16_f32 %0, %1, %2" : "=v"(r) : "v"(a), "v"(b));
  return r;
}
static __device__ inline void cvt8(const float* v, short8& hi8, short8& lo8) {
  union { short8 s; unsigned u[4]; } H, L;
  #pragma unroll
  for (int w = 0; w < 4; ++w) {
    const float f0 = v[2 * w], f1 = v[2 * w + 1];
    const unsigned u = cvtpk2(f0, f1);
    const float b0 = __uint_as_float(u << 16);
    const float b1 = __uint_as_float(u & 0xffff0000u);
    L.u[w] = cvtpk2(f0 - b0, f1 - b1);
    H.u[w] = u;
  }
  hi8 = H.s; lo8 = L.s;
}

// Fragment layout for a [R][128-k] matrix, per split:
//   short8 index = rowblk*512 + kchunk*64 + lane,  lane=(row&31)+32*((k>>3)&1)
// For W (B-operand, [128 n][2048 k]): short8 index = (tile*128 + kchunk)*64 + lane,
//   lane=(n&31)+32*((k>>3)&1), tile=n>>5.

// ---------------- K0 fused: W-split pack (blocks 0..511) + emb norm pack -------
__global__ __launch_bounds__(64) void k0_prep(const float* __restrict__ W,
                                              const float* __restrict__ emb,
                                              short* __restrict__ wHi,
                                              short* __restrict__ wLo,
                                              short* __restrict__ eHi,
                                              short* __restrict__ eLo) {
  const int l = threadIdx.x;
  if (blockIdx.x < 512) {
    const int tc = blockIdx.x;
    const int t = tc >> 7, c = tc & 127;
    const int n = t * 32 + (l & 31);
    const int k = c * 16 + (l >> 5) * 8;
    const float4 a0 = *(const float4*)&W[(size_t)n * DM + k];
    const float4 a1 = *(const float4*)&W[(size_t)n * DM + k + 4];
    const float av[8] = {a0.x, a0.y, a0.z, a0.w, a1.x, a1.y, a1.z, a1.w};
    short8 hi8, lo8; float bk;
    #pragma unroll
    for (int e = 0; e < 8; ++e) {
      hi8[e] = f2bf(av[e], bk); lo8[e] = f2bf(av[e] - bk, bk);
    }
    const size_t idx = (size_t)tc * 64 + l;
    ((short8*)wHi)[idx] = hi8;
    ((short8*)wLo)[idx] = lo8;
  } else {
    const int row = blockIdx.x - 512;          // 0..1535
    __shared__ short sh[128], sl[128];
    float2 v = *(const float2*)&emb[row * 128 + l * 2];
    float ss = v.x * v.x + v.y * v.y;
    #pragma unroll
    for (int m = 32; m; m >>= 1) ss += __shfl_xor(ss, m);
    const float inv = 1.0f / fmaxf(sqrtf(ss), 1e-12f);
    float bk;
    const float ox = v.x * inv, oy = v.y * inv;
    sh[2 * l] = f2bf(ox, bk);     sl[2 * l] = f2bf(ox - bk, bk);
    sh[2 * l + 1] = f2bf(oy, bk); sl[2 * l + 1] = f2bf(oy - bk, bk);
    __syncthreads();
    if (l < 32) {
      const int split = l >> 4, kc = (l >> 1) & 7, kh = l & 1;
      const short* src = (split ? sl : sh) + kc * 16 + kh * 8;
      const short8 val = *(const short8*)src;
      const size_t idx = (size_t)(row >> 5) * 4096 + kc * 512 +
                         ((row & 31) + 32 * kh) * 8;
      *(short8*)((split ? eLo : eHi) + idx) = val;
    }
  }
}

// ---------------- K1: h = x @ W^T + b — reg-direct, no LDS/barriers in loop ----
// grid 512 (32-row tiles), 512 thr = 8 waves = (K-half kh) x (4 col-tiles ct).
// Wave computes 32 rows x 32 cols over 1024 k. A: global->reg fp32, cvt in-reg.
// B: packed wHi/wLo from L2 (1 MB resident). 2-deep named-register pipeline,
// macro-step BK=64 (4 k-chunks). Epilogue: kh-reduce in LDS + bias + pack.
__global__ __launch_bounds__(512, 2) void k1_mfma(const float* __restrict__ x,
                                                  const short* __restrict__ wHi,
                                                  const short* __restrict__ wLo,
                                                  const float* __restrict__ bias,
                                                  short* __restrict__ hHi,
                                                  short* __restrict__ hLo) {
  __shared__ __align__(16) float hsum[32][132];   // 16.9 KB
  __shared__ float bsh[128];
  const int t = threadIdx.x;
  const int wave = t >> 6, lane = t & 63;
  const int fr = lane & 31, ks = lane >> 5;
  const int kh = wave >> 2, ct = wave & 3;
  const int m0 = blockIdx.x * 32;

  if (t < 128) bsh[t] = bias[t];

  const float* xb = x + (size_t)(m0 + fr) * DM + kh * 1024 + ks * 8;
  const short8* bhp = (const short8*)wHi + ((size_t)ct * 128 + kh * 64) * 64 + lane;
  const short8* blp = (const short8*)wLo + ((size_t)ct * 128 + kh * 64) * 64 + lane;

  f32x16 acc = {};

  // two named register sets (p, q), 12 loads each (8 A-f32x4 + 4 B-short8)
  float4 p0, p1, p2, p3, p4, p5, p6, p7;
  short8 ph0, pl0, ph1, pl1, ph2, pl2, ph3, pl3;
  float4 q0, q1, q2, q3, q4, q5, q6, q7;
  short8 qh0, ql0, qh1, ql1, qh2, ql2, qh3, ql3;

  #define LOADP { p0 = *(const float4*)(xb +  0); p1 = *(const float4*)(xb +  4); \
                  p2 = *(const float4*)(xb + 16); p3 = *(const float4*)(xb + 20); \
                  p4 = *(const float4*)(xb + 32); p5 = *(const float4*)(xb + 36); \
                  p6 = *(const float4*)(xb + 48); p7 = *(const float4*)(xb + 52); \
                  ph0 = bhp[0];   pl0 = blp[0];   ph1 = bhp[64];  pl1 = blp[64]; \
                  ph2 = bhp[128]; pl2 = blp[128]; ph3 = bhp[192]; pl3 = blp[192]; }
  #define LOADQ { q0 = *(const float4*)(xb +  0); q1 = *(const float4*)(xb +  4); \
                  q2 = *(const float4*)(xb + 16); q3 = *(const float4*)(xb + 20); \
                  q4 = *(const float4*)(xb + 32); q5 = *(const float4*)(xb + 36); \
                  q6 = *(const float4*)(xb + 48); q7 = *(const float4*)(xb + 52); \
                  qh0 = bhp[0];   ql0 = blp[0];   qh1 = bhp[64];  ql1 = blp[64]; \
                  qh2 = bhp[128]; ql2 = blp[128]; qh3 = bhp[192]; ql3 = blp[192]; }
  #define ADV { xb += 64; bhp += 256; blp += 256; }
  #define CH(x0, x1, bh, bl)                                                    \
    { const float av[8] = {x0.x, x0.y, x0.z, x0.w, x1.x, x1.y, x1.z, x1.w};     \
      short8 ah, al; cvt8(av, ah, al);                                          \
      acc = __builtin_amdgcn_mfma_f32_32x32x16_bf16(ah, bh, acc, 0, 0, 0);      \
      acc = __builtin_amdgcn_mfma_f32_32x32x16_bf16(ah, bl, acc, 0, 0, 0);      \
      acc = __builtin_amdgcn_mfma_f32_32x32x16_bf16(al, bh, acc, 0, 0, 0); }
  #define COMPP { CH(p0, p1, ph0, pl0) CH(p2, p3, ph1, pl1) \
                  CH(p4, p5, ph2, pl2) CH(p6, p7, ph3, pl3) }
  #define COMPQ { CH(q0, q1, qh0, ql0) CH(q2, q3, qh1, ql1) \
                  CH(q4, q5, qh2, ql2) CH(q6, q7, qh3, ql3) }

  LOADP; ADV;                       // macro-step 0 in flight
  #pragma unroll 1
  for (int it = 0; it < 8; ++it) {
    LOADQ; ADV;                     // macro 2it+1 in flight
    COMPP;                          // consume macro 2it (waits its own loads)
    if (it != 7) { LOADP; }         // macro 2it+2 in flight
    ADV;
    COMPQ;                          // consume macro 2it+1
  }
  #undef LOADP
  #undef LOADQ
  #undef ADV
  #undef CH
  #undef COMPP
  #undef COMPQ

  // ---- epilogue: kh-reduce (2-way) + bias + bf16-split pack ----
  if (kh == 0) {
    #pragma unroll
    for (int reg = 0; reg < 16; ++reg) {
      const int row = (reg & 3) + 8 * (reg >> 2) + 4 * ks;
      hsum[row][ct * 32 + fr] = acc[reg];
    }
  }
  __syncthreads();
  if (kh == 1) {
    #pragma unroll
    for (int reg = 0; reg < 16; ++reg) {
      const int row = (reg & 3) + 8 * (reg >> 2) + 4 * ks;
      hsum[row][ct * 32 + fr] += acc[reg];
    }
  }
  __syncthreads();
  {
    const int row = t >> 4, kc8 = t & 15;       // 512 tasks, 1 per thread
    float v[8];
    #pragma unroll
    for (int j = 0; j < 8; ++j)
      v[j] = hsum[row][kc8 * 8 + j] + bsh[kc8 * 8 + j];
    short8 hi8, lo8;
    cvt8(v, hi8, lo8);
    const int kc = kc8 >> 1, khp = kc8 & 1;
    const size_t idx = (size_t)blockIdx.x * 512 + kc * 64 + (row + 32 * khp);
    ((short8*)hHi)[idx] = hi8;
    ((short8*)hLo)[idx] = lo8;
  }
}

// ---------------- K2: logits via MFMA + softmax + weighted col-sum -------------
// grid (256 row-tiles of 64, 3 segments), 512 threads = 8 waves. (verified)
__global__ __launch_bounds__(512, 2) void k2_mfma(const short* __restrict__ hHi,
                                                  const short* __restrict__ hLo,
                                                  const short* __restrict__ eHi,
                                                  const short* __restrict__ eLo,
                                                  const float* __restrict__ imp,
                                                  float* __restrict__ partials) {
  const int t = threadIdx.x;
  const int m0 = blockIdx.x * 64;
  const int seg = blockIdx.y;
  const int wave = t >> 6, lane = t & 63;
  const int wr = wave >> 2;
  const int wc = wave & 3;
  const int fr = lane & 31;
  const int hi = lane >> 5;

  __shared__ float redA[2][32][4];
  __shared__ float redB[2][32][4];
  __shared__ float ldsD[2][512];

  f32x16 acc[4] = {};

  const short8* pAh = (const short8*)hHi + ((m0 >> 5) + wr) * 512 + lane;
  const short8* pAl = (const short8*)hLo + ((m0 >> 5) + wr) * 512 + lane;
  const short8* pBh = (const short8*)eHi + (seg * 16 + wc * 4) * 512 + lane;
  const short8* pBl = (const short8*)eLo + (seg * 16 + wc * 4) * 512 + lane;

  #pragma unroll
  for (int kc = 0; kc < 8; ++kc) {
    const short8 ah = pAh[kc * 64];
    const short8 al = pAl[kc * 64];
    #pragma unroll
    for (int t2 = 0; t2 < 4; ++t2) {
      const short8 bh = pBh[t2 * 512 + kc * 64];
      const short8 bl = pBl[t2 * 512 + kc * 64];
      acc[t2] = __builtin_amdgcn_mfma_f32_32x32x16_bf16(ah, bh, acc[t2], 0, 0, 0);
      acc[t2] = __builtin_amdgcn_mfma_f32_32x32x16_bf16(ah, bl, acc[t2], 0, 0, 0);
      acc[t2] = __builtin_amdgcn_mfma_f32_32x32x16_bf16(al, bh, acc[t2], 0, 0, 0);
    }
  }

  float mx[16];
  #pragma unroll
  for (int r = 0; r < 16; ++r) {
    float m = fmaxf(fmaxf(acc[0][r], acc[1][r]), fmaxf(acc[2][r], acc[3][r]));
    #pragma unroll
    for (int k = 1; k < 32; k <<= 1) m = fmaxf(m, __shfl_xor(m, k));
    mx[r] = m;
  }
  if (fr == 0) {
    #pragma unroll
    for (int r = 0; r < 16; ++r)
      redA[wr][(r & 3) + 8 * (r >> 2) + 4 * hi][wc] = mx[r];
  }
  __syncthreads();
  float M[16];
  #pragma unroll
  for (int r = 0; r < 16; ++r) {
    const int row = (r & 3) + 8 * (r >> 2) + 4 * hi;
    M[r] = fmaxf(fmaxf(redA[wr][row][0], redA[wr][row][1]),
                 fmaxf(redA[wr][row][2], redA[wr][row][3]));
  }

  float sm[16];
  #pragma unroll
  for (int r = 0; r < 16; ++r) {
    float s = 0.0f;
    #pragma unroll
    for (int t2 = 0; t2 < 4; ++t2) {
      const float p = __expf(acc[t2][r] - M[r]);
      acc[t2][r] = p;
      s += p;
    }
    #pragma unroll
    for (int k = 1; k < 32; k <<= 1) s += __shfl_xor(s, k);
    sm[r] = s;
  }
  if (fr == 0) {
    #pragma unroll
    for (int r = 0; r < 16; ++r)
      redB[wr][(r & 3) + 8 * (r >> 2) + 4 * hi][wc] = sm[r];
  }
  __syncthreads();
  float w[16];
  #pragma unroll
  for (int r = 0; r < 16; ++r) {
    const int row = (r & 3) + 8 * (r >> 2) + 4 * hi;
    const float S = (redB[wr][row][0] + redB[wr][row][1]) +
                    (redB[wr][row][2] + redB[wr][row][3]);
    w[r] = imp[m0 + wr * 32 + row] / S;
  }

  #pragma unroll
  for (int t2 = 0; t2 < 4; ++t2) {
    float d = 0.0f;
    #pragma unroll
    for (int r = 0; r < 16; ++r) d = fmaf(acc[t2][r], w[r], d);
    d += __shfl_xor(d, 32);
    if (hi == 0) ldsD[wr][wc * 128 + t2 * 32 + fr] = d;
  }
  __syncthreads();
  partials[((size_t)seg * 256 + blockIdx.x) * 512 + t] = ldsD[0][t] + ldsD[1][t];
}

// ---------------- K3: sum partials (fixed order) + top-k + write ---------------
__global__ __launch_bounds__(256) void k3_topk(const float* __restrict__ partials,
                                               float* __restrict__ out) {
  const int b = blockIdx.x;
  const int seg = blockIdx.y;
  const int tid = threadIdx.x;
  const int K = (seg == 0) ? 8 : ((seg == 1) ? 4 : 6);

  __shared__ float v[512];
  __shared__ float wv[8];
  __shared__ int wi[8];
  __shared__ float redv[4];
  __shared__ int redi[4];

  const float* src = partials + ((size_t)seg * 256 + b * 64) * 512;
  float a0 = 0.f, a1 = 0.f, a2 = 0.f, a3 = 0.f;
  float b0 = 0.f, b1 = 0.f, b2 = 0.f, b3 = 0.f;
  for (int j = 0; j < 64; j += 4) {
    a0 += src[(size_t)(j + 0) * 512 + tid];
    a1 += src[(size_t)(j + 1) * 512 + tid];
    a2 += src[(size_t)(j + 2) * 512 + tid];
    a3 += src[(size_t)(j + 3) * 512 + tid];
    b0 += src[(size_t)(j + 0) * 512 + tid + 256];
    b1 += src[(size_t)(j + 1) * 512 + tid + 256];
    b2 += src[(size_t)(j + 2) * 512 + tid + 256];
    b3 += src[(size_t)(j + 3) * 512 + tid + 256];
  }
  v[tid] = (a0 + a1) + (a2 + a3);
  v[tid + 256] = (b0 + b1) + (b2 + b3);
  __syncthreads();

  for (int t = 0; t < K; ++t) {
    const float v0 = v[tid], v1 = v[tid + 256];
    float bv; int bi;
    if (v1 > v0) { bv = v1; bi = tid + 256; } else { bv = v0; bi = tid; }
    #pragma unroll
    for (int m = 1; m < 64; m <<= 1) {
      const float ov = __shfl_xor(bv, m);
      const int oi = __shfl_xor(bi, m);
      if (ov > bv || (ov == bv && oi < bi)) { bv = ov; bi = oi; }
    }
    if ((tid & 63) == 0) { redv[tid >> 6] = bv; redi[tid >> 6] = bi; }
    __syncthreads();
    if (tid == 0) {
      float best = redv[0]; int besti = redi[0];
      for (int q = 1; q < 4; ++q)
        if (redv[q] > best || (redv[q] == best && redi[q] < besti)) {
          best = redv[q]; besti = redi[q];
        }
      wv[t] = best; wi[t] = besti;
      v[besti] = -3.0e38f;
    }
    __syncthreads();
  }

  float s = 1e-8f;
  for (int t = 0; t < K; ++t) s += wv[t];

  const int slot0 = (seg == 0) ? 0 : ((seg == 1) ? 1 : 3);
  float* o0 = out + slot0 * (BATCH * NSEG) + b * NSEG;
  o0[tid] = 0.0f; o0[tid + 256] = 0.0f;
  float* o1 = nullptr;
  if (seg == 1) {
    o1 = out + 2 * (BATCH * NSEG) + b * NSEG;
    o1[tid] = 0.0f; o1[tid + 256] = 0.0f;
  }
  __syncthreads();
  if (tid < K) {
    const float val = wv[tid] / s;
    o0[wi[tid]] = val;
    if (seg == 1) o1[wi[tid]] = val;
  }
}

// -------------------------------- launch ---------------------------------------
extern "C" void kernel_launch(void* const* d_in, const int* in_sizes, int n_in,
                              void* d_out, int out_size, void* d_ws, size_t ws_size,
                              hipStream_t stream) {
  (void)in_sizes; (void)n_in; (void)out_size; (void)ws_size;
  const float* x    = (const float*)d_in[0];
  const float* imp  = (const float*)d_in[1];
  const float* W    = (const float*)d_in[2];
  const float* bias = (const float*)d_in[3];
  const float* emb  = (const float*)d_in[4];
  float* out = (float*)d_out;

  // workspace carve: partials (f32), then hHi | hLo | eHi | eLo | wHi | wLo (i16)
  float* partials = (float*)d_ws;                     // 393216 f32
  short* hHi      = (short*)(partials + 393216);      // 2097152 i16
  short* hLo      = hHi + 2097152;
  short* eHi      = hLo + 2097152;                    // 196608 i16
  short* eLo      = eHi + 196608;
  short* wHi      = eLo + 196608;                     // 262144 i16
  short* wLo      = wHi + 262144;

  k0_prep<<<512 + 1536, 64, 0, stream>>>(W, emb, wHi, wLo, eHi, eLo);
  k1_mfma<<<ROWS / 32, 512, 0, stream>>>(x, wHi, wLo, bias, hHi, hLo);
  k2_mfma<<<dim3(ROWS / 64, 3), 512, 0, stream>>>(hHi, hLo, eHi, eLo, imp, partials);
  k3_topk<<<dim3(BATCH, 3), 256, 0, stream>>>(partials, out);
}

// Round 10
// 97.893 us; speedup vs baseline: 1.4174x; 1.4174x over previous
//
#include <hip/hip_runtime.h>
#include <hip/hip_bf16.h>

// Problem constants
#define BATCH 4
#define S_TOT 4096
#define ROWS (BATCH * S_TOT)   // 16384
#define DM 2048
#define DSP 128
#define NSEG 512               // neurons per segment; 3 segments

typedef short short8 __attribute__((ext_vector_type(8)));
typedef float f32x16 __attribute__((ext_vector_type(16)));

// float -> bf16(RNE) bits; also returns the fp32 value of the bf16 for residual
static __device__ inline short f2bf(float v, float& back) {
  unsigned u = __float_as_uint(v);
  unsigned r = u + 0x7FFFu + ((u >> 16) & 1u);
  unsigned short hs = (unsigned short)(r >> 16);
  back = __uint_as_float(((unsigned)hs) << 16);
  return (short)hs;
}

// packed f32x2 -> bf16x2 (hw instr). Lo term is exact residual of hi's value,
// so the split is correct regardless of cvt rounding mode.
static __device__ inline unsigned cvtpk2(float a, float b) {
  unsigned r;
  asm("v_cvt_pk_bf16_f32 %0, %1, %2" : "=v"(r) : "v"(a), "v"(b));
  return r;
}
static __device__ inline void cvt8(const float* v, short8& hi8, short8& lo8) {
  union { short8 s; unsigned u[4]; } H, L;
  #pragma unroll
  for (int w = 0; w < 4; ++w) {
    const float f0 = v[2 * w], f1 = v[2 * w + 1];
    const unsigned u = cvtpk2(f0, f1);
    const float b0 = __uint_as_float(u << 16);
    const float b1 = __uint_as_float(u & 0xffff0000u);
    L.u[w] = cvtpk2(f0 - b0, f1 - b1);
    H.u[w] = u;
  }
  hi8 = H.s; lo8 = L.s;
}

// global_load_lds, 16B per lane: per-lane global src, wave-uniform LDS dst
#define GLL16(gsrc, ldst)                                                       \
  __builtin_amdgcn_global_load_lds(                                             \
      (const __attribute__((address_space(1))) void*)(gsrc),                    \
      (__attribute__((address_space(3))) void*)(ldst), 16, 0, 0)

#define SBAR   __builtin_amdgcn_s_barrier()
#define SCHEDB __builtin_amdgcn_sched_barrier(0)

// Fragment layout for a [R][128-k] matrix, per split:
//   short8 index = rowblk*512 + kchunk*64 + lane,  lane=(row&31)+32*((k>>3)&1)
// For W (B-operand, [128 n][2048 k]): short8 index = (tile*128 + kchunk)*64 + lane,
//   lane=(n&31)+32*((k>>3)&1), tile=n>>5.

// ---------------- K0 fused: W-split pack (blocks 0..511) + emb norm pack -------
__global__ __launch_bounds__(64) void k0_prep(const float* __restrict__ W,
                                              const float* __restrict__ emb,
                                              short* __restrict__ wHi,
                                              short* __restrict__ wLo,
                                              short* __restrict__ eHi,
                                              short* __restrict__ eLo) {
  const int l = threadIdx.x;
  if (blockIdx.x < 512) {
    const int tc = blockIdx.x;
    const int t = tc >> 7, c = tc & 127;
    const int n = t * 32 + (l & 31);
    const int k = c * 16 + (l >> 5) * 8;
    const float4 a0 = *(const float4*)&W[(size_t)n * DM + k];
    const float4 a1 = *(const float4*)&W[(size_t)n * DM + k + 4];
    const float av[8] = {a0.x, a0.y, a0.z, a0.w, a1.x, a1.y, a1.z, a1.w};
    short8 hi8, lo8; float bk;
    #pragma unroll
    for (int e = 0; e < 8; ++e) {
      hi8[e] = f2bf(av[e], bk); lo8[e] = f2bf(av[e] - bk, bk);
    }
    const size_t idx = (size_t)tc * 64 + l;
    ((short8*)wHi)[idx] = hi8;
    ((short8*)wLo)[idx] = lo8;
  } else {
    const int row = blockIdx.x - 512;          // 0..1535
    __shared__ short sh[128], sl[128];
    float2 v = *(const float2*)&emb[row * 128 + l * 2];
    float ss = v.x * v.x + v.y * v.y;
    #pragma unroll
    for (int m = 32; m; m >>= 1) ss += __shfl_xor(ss, m);
    const float inv = 1.0f / fmaxf(sqrtf(ss), 1e-12f);
    float bk;
    const float ox = v.x * inv, oy = v.y * inv;
    sh[2 * l] = f2bf(ox, bk);     sl[2 * l] = f2bf(ox - bk, bk);
    sh[2 * l + 1] = f2bf(oy, bk); sl[2 * l + 1] = f2bf(oy - bk, bk);
    __syncthreads();
    if (l < 32) {
      const int split = l >> 4, kc = (l >> 1) & 7, kh = l & 1;
      const short* src = (split ? sl : sh) + kc * 16 + kh * 8;
      const short8 val = *(const short8*)src;
      const size_t idx = (size_t)(row >> 5) * 4096 + kc * 512 +
                         ((row & 31) + 32 * kh) * 8;
      *(short8*)((split ? eLo : eHi) + idx) = val;
    }
  }
}

// ---------------- K1: h = x @ W^T + b — coalesced GLL, 3-buf, counted vmcnt ----
// grid 512 (32-row tiles), 256 thr = 4 waves; wave = one 32-col tile, full K.
// Per step (BK=64): 8 line-coalesced GLL16 (2/wave), 8 B loads/wave from packed
// W (L2), 8 ds_read_b128/wave + cvt + 12 MFMA. One s_barrier per step; B issued
// BEFORE the stage GLLs so MFMA's implicit vmcnt waits never drain the prefetch.
__global__ __launch_bounds__(256, 2) void k1_mfma(const float* __restrict__ x,
                                                  const short* __restrict__ wHi,
                                                  const short* __restrict__ wLo,
                                                  const float* __restrict__ bias,
                                                  short* __restrict__ hHi,
                                                  short* __restrict__ hLo) {
  __shared__ __align__(16) float As[3][32][64];   // 3 bufs x 8 KB
  __shared__ __align__(16) float hsum[32][132];
  __shared__ float bsh[128];
  const int t = threadIdx.x;
  const int wave = t >> 6, lane = t & 63;          // wave = col-tile ct
  const int fr = lane & 31, ks = lane >> 5;
  const int m0 = blockIdx.x * 32;

  if (t < 128) bsh[t] = bias[t];

  // Staging: wave w, instr j in {0,1} covers rows 8w+4j .. +3 (4 rows x 256B).
  // lane l: row = 8w+4j+(l>>4); granule gl = l&15 (16B units);
  // source granule = (gl&8) | ((gl&7) ^ (row&7))  [low-3-bit XOR swizzle;
  // permutes within each 128B line -> still perfectly line-coalesced].
  const int r0 = 8 * wave + (lane >> 4);           // j=0 row
  const int r1 = r0 + 4;                           // j=1 row
  const int gl = lane & 15;
  const int g0s = (gl & 8) | ((gl & 7) ^ (r0 & 7));
  const int g1s = (gl & 8) | ((gl & 7) ^ (r1 & 7));
  const float* xs0 = x + (size_t)(m0 + r0) * DM + g0s * 4;
  const float* xs1 = x + (size_t)(m0 + r1) * DM + g1s * 4;

  const short8* bhp = (const short8*)wHi + (size_t)wave * 128 * 64 + lane;
  const short8* blp = (const short8*)wLo + (size_t)wave * 128 * 64 + lane;

  f32x16 acc = {};

  #define STAGE(buf, s)                                                         \
    {                                                                           \
      GLL16(xs0 + (s) * 64, &As[buf][8 * wave][0]);                             \
      GLL16(xs1 + (s) * 64, &As[buf][8 * wave + 4][0]);                         \
    }

  STAGE(0, 0);
  STAGE(1, 1);

  const int f7 = fr & 7;
  #pragma unroll 1
  for (int s = 0; s < 32; ++s) {
    if (s < 31) { asm volatile("s_waitcnt vmcnt(2)" ::: "memory"); }
    else        { asm volatile("s_waitcnt vmcnt(0)" ::: "memory"); }
    SBAR; SCHEDB;

    const int buf = s % 3;
    // ---- B loads first (older than the stage GLLs) ----
    const size_t kc0 = (size_t)s * 4;
    const short8 bh0 = bhp[(kc0 + 0) * 64], bl0 = blp[(kc0 + 0) * 64];
    const short8 bh1 = bhp[(kc0 + 1) * 64], bl1 = blp[(kc0 + 1) * 64];
    const short8 bh2 = bhp[(kc0 + 2) * 64], bl2 = blp[(kc0 + 2) * 64];
    const short8 bh3 = bhp[(kc0 + 3) * 64], bl3 = blp[(kc0 + 3) * 64];
    SCHEDB;
    // ---- prefetch stage s+2 into buf (s+2)%3 (never the buf being read) ----
    if (s + 2 < 32) STAGE((s + 2) % 3, s + 2);
    SCHEDB;

    // ---- A ds_read + cvt + MFMA (registers + LDS only) ----
    const float* Ar = &As[buf][fr][0];
    #define CHUNK(c, bh, bl)                                                    \
    {                                                                           \
      const int g0 = (c) * 4 + ks * 2;                                          \
      const int p0 = (g0 & 8) | ((g0 & 7) ^ f7);                                \
      const int p1 = ((g0 + 1) & 8) | (((g0 + 1) & 7) ^ f7);                    \
      const float4 a0 = *(const float4*)(Ar + p0 * 4);                          \
      const float4 a1 = *(const float4*)(Ar + p1 * 4);                          \
      const float av[8] = {a0.x, a0.y, a0.z, a0.w, a1.x, a1.y, a1.z, a1.w};     \
      short8 ah, al; cvt8(av, ah, al);                                          \
      acc = __builtin_amdgcn_mfma_f32_32x32x16_bf16(ah, bh, acc, 0, 0, 0);      \
      acc = __builtin_amdgcn_mfma_f32_32x32x16_bf16(ah, bl, acc, 0, 0, 0);      \
      acc = __builtin_amdgcn_mfma_f32_32x32x16_bf16(al, bh, acc, 0, 0, 0);      \
    }
    CHUNK(0, bh0, bl0)
    CHUNK(1, bh1, bl1)
    CHUNK(2, bh2, bl2)
    CHUNK(3, bh3, bl3)
    #undef CHUNK
  }
  #undef STAGE

  // ---- epilogue: acc -> LDS, add bias, bf16-split pack (no reduce needed) ----
  #pragma unroll
  for (int reg = 0; reg < 16; ++reg) {
    const int row = (reg & 3) + 8 * (reg >> 2) + 4 * ks;
    hsum[row][wave * 32 + fr] = acc[reg];
  }
  __syncthreads();
  #pragma unroll
  for (int i = 0; i < 2; ++i) {
    const int task = t + 256 * i;                // 512 tasks: 32 rows x 16 kc8
    const int row = task >> 4, kc8 = task & 15;
    float v[8];
    #pragma unroll
    for (int j = 0; j < 8; ++j)
      v[j] = hsum[row][kc8 * 8 + j] + bsh[kc8 * 8 + j];
    short8 hi8, lo8;
    cvt8(v, hi8, lo8);
    const int kc = kc8 >> 1, khp = kc8 & 1;
    const size_t idx = (size_t)blockIdx.x * 512 + kc * 64 + (row + 32 * khp);
    ((short8*)hHi)[idx] = hi8;
    ((short8*)hLo)[idx] = lo8;
  }
}

// ---------------- K2: logits via MFMA + softmax + weighted col-sum -------------
// grid (256 row-tiles of 64, 3 segments), 512 threads = 8 waves. (verified)
__global__ __launch_bounds__(512, 2) void k2_mfma(const short* __restrict__ hHi,
                                                  const short* __restrict__ hLo,
                                                  const short* __restrict__ eHi,
                                                  const short* __restrict__ eLo,
                                                  const float* __restrict__ imp,
                                                  float* __restrict__ partials) {
  const int t = threadIdx.x;
  const int m0 = blockIdx.x * 64;
  const int seg = blockIdx.y;
  const int wave = t >> 6, lane = t & 63;
  const int wr = wave >> 2;
  const int wc = wave & 3;
  const int fr = lane & 31;
  const int hi = lane >> 5;

  __shared__ float redA[2][32][4];
  __shared__ float redB[2][32][4];
  __shared__ float ldsD[2][512];

  f32x16 acc[4] = {};

  const short8* pAh = (const short8*)hHi + ((m0 >> 5) + wr) * 512 + lane;
  const short8* pAl = (const short8*)hLo + ((m0 >> 5) + wr) * 512 + lane;
  const short8* pBh = (const short8*)eHi + (seg * 16 + wc * 4) * 512 + lane;
  const short8* pBl = (const short8*)eLo + (seg * 16 + wc * 4) * 512 + lane;

  #pragma unroll
  for (int kc = 0; kc < 8; ++kc) {
    const short8 ah = pAh[kc * 64];
    const short8 al = pAl[kc * 64];
    #pragma unroll
    for (int t2 = 0; t2 < 4; ++t2) {
      const short8 bh = pBh[t2 * 512 + kc * 64];
      const short8 bl = pBl[t2 * 512 + kc * 64];
      acc[t2] = __builtin_amdgcn_mfma_f32_32x32x16_bf16(ah, bh, acc[t2], 0, 0, 0);
      acc[t2] = __builtin_amdgcn_mfma_f32_32x32x16_bf16(ah, bl, acc[t2], 0, 0, 0);
      acc[t2] = __builtin_amdgcn_mfma_f32_32x32x16_bf16(al, bh, acc[t2], 0, 0, 0);
    }
  }

  float mx[16];
  #pragma unroll
  for (int r = 0; r < 16; ++r) {
    float m = fmaxf(fmaxf(acc[0][r], acc[1][r]), fmaxf(acc[2][r], acc[3][r]));
    #pragma unroll
    for (int k = 1; k < 32; k <<= 1) m = fmaxf(m, __shfl_xor(m, k));
    mx[r] = m;
  }
  if (fr == 0) {
    #pragma unroll
    for (int r = 0; r < 16; ++r)
      redA[wr][(r & 3) + 8 * (r >> 2) + 4 * hi][wc] = mx[r];
  }
  __syncthreads();
  float M[16];
  #pragma unroll
  for (int r = 0; r < 16; ++r) {
    const int row = (r & 3) + 8 * (r >> 2) + 4 * hi;
    M[r] = fmaxf(fmaxf(redA[wr][row][0], redA[wr][row][1]),
                 fmaxf(redA[wr][row][2], redA[wr][row][3]));
  }

  float sm[16];
  #pragma unroll
  for (int r = 0; r < 16; ++r) {
    float s = 0.0f;
    #pragma unroll
    for (int t2 = 0; t2 < 4; ++t2) {
      const float p = __expf(acc[t2][r] - M[r]);
      acc[t2][r] = p;
      s += p;
    }
    #pragma unroll
    for (int k = 1; k < 32; k <<= 1) s += __shfl_xor(s, k);
    sm[r] = s;
  }
  if (fr == 0) {
    #pragma unroll
    for (int r = 0; r < 16; ++r)
      redB[wr][(r & 3) + 8 * (r >> 2) + 4 * hi][wc] = sm[r];
  }
  __syncthreads();
  float w[16];
  #pragma unroll
  for (int r = 0; r < 16; ++r) {
    const int row = (r & 3) + 8 * (r >> 2) + 4 * hi;
    const float S = (redB[wr][row][0] + redB[wr][row][1]) +
                    (redB[wr][row][2] + redB[wr][row][3]);
    w[r] = imp[m0 + wr * 32 + row] / S;
  }

  #pragma unroll
  for (int t2 = 0; t2 < 4; ++t2) {
    float d = 0.0f;
    #pragma unroll
    for (int r = 0; r < 16; ++r) d = fmaf(acc[t2][r], w[r], d);
    d += __shfl_xor(d, 32);
    if (hi == 0) ldsD[wr][wc * 128 + t2 * 32 + fr] = d;
  }
  __syncthreads();
  partials[((size_t)seg * 256 + blockIdx.x) * 512 + t] = ldsD[0][t] + ldsD[1][t];
}

// ---------------- K3: sum partials (fixed order) + top-k + write ---------------
__global__ __launch_bounds__(256) void k3_topk(const float* __restrict__ partials,
                                               float* __restrict__ out) {
  const int b = blockIdx.x;
  const int seg = blockIdx.y;
  const int tid = threadIdx.x;
  const int K = (seg == 0) ? 8 : ((seg == 1) ? 4 : 6);

  __shared__ float v[512];
  __shared__ float wv[8];
  __shared__ int wi[8];
  __shared__ float redv[4];
  __shared__ int redi[4];

  const float* src = partials + ((size_t)seg * 256 + b * 64) * 512;
  float a0 = 0.f, a1 = 0.f, a2 = 0.f, a3 = 0.f;
  float b0 = 0.f, b1 = 0.f, b2 = 0.f, b3 = 0.f;
  for (int j = 0; j < 64; j += 4) {
    a0 += src[(size_t)(j + 0) * 512 + tid];
    a1 += src[(size_t)(j + 1) * 512 + tid];
    a2 += src[(size_t)(j + 2) * 512 + tid];
    a3 += src[(size_t)(j + 3) * 512 + tid];
    b0 += src[(size_t)(j + 0) * 512 + tid + 256];
    b1 += src[(size_t)(j + 1) * 512 + tid + 256];
    b2 += src[(size_t)(j + 2) * 512 + tid + 256];
    b3 += src[(size_t)(j + 3) * 512 + tid + 256];
  }
  v[tid] = (a0 + a1) + (a2 + a3);
  v[tid + 256] = (b0 + b1) + (b2 + b3);
  __syncthreads();

  for (int t = 0; t < K; ++t) {
    const float v0 = v[tid], v1 = v[tid + 256];
    float bv; int bi;
    if (v1 > v0) { bv = v1; bi = tid + 256; } else { bv = v0; bi = tid; }
    #pragma unroll
    for (int m = 1; m < 64; m <<= 1) {
      const float ov = __shfl_xor(bv, m);
      const int oi = __shfl_xor(bi, m);
      if (ov > bv || (ov == bv && oi < bi)) { bv = ov; bi = oi; }
    }
    if ((tid & 63) == 0) { redv[tid >> 6] = bv; redi[tid >> 6] = bi; }
    __syncthreads();
    if (tid == 0) {
      float best = redv[0]; int besti = redi[0];
      for (int q = 1; q < 4; ++q)
        if (redv[q] > best || (redv[q] == best && redi[q] < besti)) {
          best = redv[q]; besti = redi[q];
        }
      wv[t] = best; wi[t] = besti;
      v[besti] = -3.0e38f;
    }
    __syncthreads();
  }

  float s = 1e-8f;
  for (int t = 0; t < K; ++t) s += wv[t];

  const int slot0 = (seg == 0) ? 0 : ((seg == 1) ? 1 : 3);
  float* o0 = out + slot0 * (BATCH * NSEG) + b * NSEG;
  o0[tid] = 0.0f; o0[tid + 256] = 0.0f;
  float* o1 = nullptr;
  if (seg == 1) {
    o1 = out + 2 * (BATCH * NSEG) + b * NSEG;
    o1[tid] = 0.0f; o1[tid + 256] = 0.0f;
  }
  __syncthreads();
  if (tid < K) {
    const float val = wv[tid] / s;
    o0[wi[tid]] = val;
    if (seg == 1) o1[wi[tid]] = val;
  }
}

// -------------------------------- launch ---------------------------------------
extern "C" void kernel_launch(void* const* d_in, const int* in_sizes, int n_in,
                              void* d_out, int out_size, void* d_ws, size_t ws_size,
                              hipStream_t stream) {
  (void)in_sizes; (void)n_in; (void)out_size; (void)ws_size;
  const float* x    = (const float*)d_in[0];
  const float* imp  = (const float*)d_in[1];
  const float* W    = (const float*)d_in[2];
  const float* bias = (const float*)d_in[3];
  const float* emb  = (const float*)d_in[4];
  float* out = (float*)d_out;

  // workspace carve: partials (f32), then hHi | hLo | eHi | eLo | wHi | wLo (i16)
  float* partials = (float*)d_ws;                     // 393216 f32
  short* hHi      = (short*)(partials + 393216);      // 2097152 i16
  short* hLo      = hHi + 2097152;
  short* eHi      = hLo + 2097152;                    // 196608 i16
  short* eLo      = eHi + 196608;
  short* wHi      = eLo + 196608;                     // 262144 i16
  short* wLo      = wHi + 262144;

  k0_prep<<<512 + 1536, 64, 0, stream>>>(W, emb, wHi, wLo, eHi, eLo);
  k1_mfma<<<ROWS / 32, 256, 0, stream>>>(x, wHi, wLo, bias, hHi, hLo);
  k2_mfma<<<dim3(ROWS / 64, 3), 512, 0, stream>>>(hHi, hLo, eHi, eLo, imp, partials);
  k3_topk<<<dim3(BATCH, 3), 256, 0, stream>>>(partials, out);
}